// Round 2
// baseline (60.318 us; speedup 1.0000x reference)
//
#include <hip/hip_runtime.h>

// NeuralQuantizer: out[i] = nearest center to x[i], centers = linspace(-1,1,256).
// Closed form: idx = clamp(round((x+1)*127.5), 0, 255); q = -1 + idx*(2/255).
// Memory-bound elementwise op (16.8 MB total traffic, floor ~2.7 us @ 6.3 TB/s).
//
// R2: 4x float4 per thread (block-strided, all loads lane-contiguous 16 B),
// nontemporal on BOTH loads and stores (input never re-read, output never
// read, L2 is poison-cold every iteration). 512 blocks x 256 thr = 8 waves/CU,
// 4 independent loads in flight per thread. Quantization math kept
// bit-identical (tie-breaking at midpoints is threshold-sensitive: absmax
// already sits at exactly one level spacing).

typedef float f32x4 __attribute__((ext_vector_type(4)));

__device__ __forceinline__ float quant1(float v) {
    float t = (v + 1.0f) * 127.5f;          // keep exact op order (ties!)
    float idx = __builtin_rintf(t);          // round-to-nearest-even
    idx = fminf(fmaxf(idx, 0.0f), 255.0f);   // clamp -> v_med3 style
    return fmaf(idx, 2.0f / 255.0f, -1.0f);
}

__device__ __forceinline__ f32x4 quant4(f32x4 v) {
    f32x4 o;
    o.x = quant1(v.x);
    o.y = quant1(v.y);
    o.z = quant1(v.z);
    o.w = quant1(v.w);
    return o;
}

__global__ __launch_bounds__(256) void quantize_f4x4(const f32x4* __restrict__ x,
                                                     f32x4* __restrict__ out,
                                                     int n4) {
    // Each block owns a contiguous chunk of 1024 float4s (256 threads x 4).
    int base = blockIdx.x * 1024 + threadIdx.x;
    int i0 = base;
    int i1 = base + 256;
    int i2 = base + 512;
    int i3 = base + 768;
    if (i3 < n4) {
        // Fast path (always taken for the fixed problem size): 4 independent
        // nontemporal loads issued back-to-back, then 4 nontemporal stores.
        f32x4 a = __builtin_nontemporal_load(&x[i0]);
        f32x4 b = __builtin_nontemporal_load(&x[i1]);
        f32x4 c = __builtin_nontemporal_load(&x[i2]);
        f32x4 d = __builtin_nontemporal_load(&x[i3]);
        __builtin_nontemporal_store(quant4(a), &out[i0]);
        __builtin_nontemporal_store(quant4(b), &out[i1]);
        __builtin_nontemporal_store(quant4(c), &out[i2]);
        __builtin_nontemporal_store(quant4(d), &out[i3]);
    } else {
        #pragma unroll
        for (int k = 0; k < 4; ++k) {
            int i = base + k * 256;
            if (i < n4) {
                f32x4 a = __builtin_nontemporal_load(&x[i]);
                __builtin_nontemporal_store(quant4(a), &out[i]);
            }
        }
    }
}

extern "C" void kernel_launch(void* const* d_in, const int* in_sizes, int n_in,
                              void* d_out, int out_size, void* d_ws, size_t ws_size,
                              hipStream_t stream) {
    const f32x4* x = (const f32x4*)d_in[0];
    f32x4* out = (f32x4*)d_out;
    int n = in_sizes[0];                 // 2,097,152 elements — divisible by 4
    int n4 = n / 4;                      // 524,288 float4s
    int per_block = 1024;                // 256 threads x 4 float4
    int grid = (n4 + per_block - 1) / per_block;   // 512 blocks
    quantize_f4x4<<<grid, 256, 0, stream>>>(x, out, n4);
}